// Round 16
// baseline (141.431 us; speedup 1.0000x reference)
//
#include <hip/hip_runtime.h>
#include <hip/hip_bf16.h>
#include <cstdint>

#define DEVINL __device__ __forceinline__

typedef __attribute__((ext_vector_type(8))) short short8;   // 8 bf16 in 4 VGPRs
typedef __attribute__((ext_vector_type(4))) float f32x4;
typedef __attribute__((ext_vector_type(4))) unsigned short u16x4;

static constexpr int NB = 64, LL = 258, HH = 1024, QQ = 256;
static constexpr int WROWS = 33;          // max window length (2*16+1)
static constexpr int MU = 2176;           // 64*33 = 2112 padded to 17*128
static constexpr int VTN = 4096;          // VT col stride: 64 n * 64 li

// ---- workspace layout (bytes) ----
static constexpr size_t OFF_META = 0;
static constexpr size_t SZ_WE   = (size_t)MU * HH * 2;
static constexpr size_t OFF_WEHI = 1024;
static constexpr size_t OFF_WELO = OFF_WEHI + SZ_WE;
static constexpr size_t OFF_WAHI = OFF_WELO + SZ_WE;
static constexpr size_t OFF_WALO = OFF_WAHI + (size_t)HH * HH * 2;
static constexpr size_t OFF_WCBF = OFF_WALO + (size_t)HH * HH * 2;
static constexpr size_t OFF_HBF  = OFF_WCBF + (size_t)HH * 2 * HH * 2;  // ht bf16 (written by k_attn2)
static constexpr size_t OFF_U    = OFF_HBF + (size_t)NB * QQ * HH * 2;
static constexpr size_t OFF_UHI  = OFF_U;
static constexpr size_t OFF_ULO  = OFF_U + (size_t)MU * HH * 2;
static constexpr size_t OFF_PHL  = OFF_U + (size_t)MU * HH * 4;         // P hi/lo bf16 [16384][128]
static constexpr size_t OFF_VT   = OFF_PHL + (size_t)NB * QQ * 128 * 2; // VT bf16 [1024][4096]

DEVINL unsigned short f2bf(float x) {
    union { float f; uint32_t u; } v; v.f = x;
    uint32_t u = v.u;
    uint32_t r = (u + 0x7FFFu + ((u >> 16) & 1u)) >> 16;
    return (unsigned short)r;
}
DEVINL float bf2f(unsigned short b) {
    union { uint32_t u; float f; } v; v.u = ((uint32_t)b) << 16;
    return v.f;
}

template <typename T>
DEVINL void lds_load16(const T* g, T* l) {
    __builtin_amdgcn_global_load_lds(
        (const __attribute__((address_space(1))) void*)g,
        (__attribute__((address_space(3))) void*)l, 16, 0, 0);
}

DEVINL float fast_tanh(float x) {
    float e = __expf(2.0f * x);
    return 1.0f - 2.0f / (e + 1.0f);
}

DEVINL void window_of(float p, int sl, int& ls, int& lc) {
    float se = (float)sl;
    float s = fmaxf(p - 16.0f, 0.0f);
    float e = fminf(p + 16.0f, se);
    ls = (int)ceilf(s);
    int le = (int)floorf(e); if (le > LL - 1) le = LL - 1;
    lc = le - ls + 1;
    if (lc < 0) lc = 0;
    if (lc > WROWS) lc = WROWS;
}

// ---------------- K_prep: gather + Wa-split + Wc-bf (5248 blocks) ----------------
__global__ __launch_bounds__(256) void k_prep(const float* __restrict__ enc,
                                              const float* __restrict__ pt,
                                              const int* __restrict__ slen,
                                              const float* __restrict__ Wa,
                                              const float* __restrict__ Wc,
                                              unsigned short* __restrict__ wehi,
                                              unsigned short* __restrict__ welo,
                                              unsigned short* __restrict__ wahi,
                                              unsigned short* __restrict__ walo,
                                              unsigned short* __restrict__ wcbf) {
    const int b = blockIdx.x, t = threadIdx.x;
    if (b < MU) {
        int r = b;
        const float* src = nullptr;
        bool valid = false;
        if (r < NB * WROWS) {
            int n = r / WROWS, li = r - n * WROWS;
            int ls, lc;
            window_of(pt[n], slen[n], ls, lc);
            if (li < lc) { valid = true; src = enc + ((size_t)n * LL + ls + li) * HH; }
        }
        f32x4 v;
        if (valid) v = ((const f32x4*)src)[t];
        else { v[0] = 0.f; v[1] = 0.f; v[2] = 0.f; v[3] = 0.f; }
        u16x4 h, l;
#pragma unroll
        for (int j = 0; j < 4; ++j) {
            unsigned short hb = f2bf(v[j]);
            h[j] = hb;
            l[j] = f2bf(v[j] - bf2f(hb));
        }
        size_t o = (size_t)r * HH / 4 + t;
        ((u16x4*)wehi)[o] = h;
        ((u16x4*)welo)[o] = l;
    } else if (b < MU + 1024) {
        int i = (b - MU) * 256 + t;
        f32x4 v = ((const f32x4*)Wa)[i];
        u16x4 h, l;
#pragma unroll
        for (int j = 0; j < 4; ++j) {
            unsigned short hb = f2bf(v[j]);
            h[j] = hb;
            l[j] = f2bf(v[j] - bf2f(hb));
        }
        ((u16x4*)wahi)[i] = h;
        ((u16x4*)walo)[i] = l;
    } else {
        int i = (b - MU - 1024) * 256 + t;
        f32x4 v = ((const f32x4*)Wc)[i];
        u16x4 h;
#pragma unroll
        for (int j = 0; j < 4; ++j) h[j] = f2bf(v[j]);
        ((u16x4*)wcbf)[i] = h;
    }
}

// ---------------- K4: merged U-GEMM + V-GEMM (pure GEMM, 544 blocks) ----------------
__global__ __launch_bounds__(256) void k_wgemm(const unsigned short* __restrict__ wehi,
                                               const unsigned short* __restrict__ welo,
                                               const unsigned short* __restrict__ wahi,
                                               const unsigned short* __restrict__ walo,
                                               const unsigned short* __restrict__ wcbf,
                                               unsigned short* __restrict__ Uhi,
                                               unsigned short* __restrict__ Ulo,
                                               unsigned short* __restrict__ VT) {
    __shared__ unsigned short smem[24576];   // 48 KB
    const int tid = threadIdx.x;
    const int bid = blockIdx.x;

    const int w = tid >> 6, lane = tid & 63;
    const int wr = w >> 1, wc = w & 1;
    const int r16 = lane & 15, khalf = lane >> 4, rg = lane >> 4;
    const int srow = tid >> 2;
    const int scol = ((tid & 3) ^ ((tid >> 3) & 3)) * 8;
    const int kslot = (khalf ^ ((r16 >> 1) & 3)) * 8;

    if (bid < 272) {
        // ---------- U-GEMM ----------
        const int m0 = (bid >> 3) * 64;
        const int n0 = (bid & 7) * 128;
        f32x4 acc[2][4] = {};

        auto stage = [&](int buf, int kb) {
            lds_load16(wehi + (size_t)(m0 + srow) * HH + kb + scol, &smem[buf * 2048 + tid * 8]);
            lds_load16(welo + (size_t)(m0 + srow) * HH + kb + scol, &smem[4096 + buf * 2048 + tid * 8]);
#pragma unroll
            for (int i = 0; i < 2; ++i) {
                lds_load16(wahi + (size_t)(n0 + i * 64 + srow) * HH + kb + scol,
                           &smem[8192 + buf * 4096 + i * 2048 + tid * 8]);
                lds_load16(walo + (size_t)(n0 + i * 64 + srow) * HH + kb + scol,
                           &smem[16384 + buf * 4096 + i * 2048 + tid * 8]);
            }
        };

        stage(0, 0);
        for (int t = 0; t < 32; ++t) {
            const int buf = t & 1;
            asm volatile("s_waitcnt vmcnt(0)" ::: "memory");
            __builtin_amdgcn_s_barrier();
            short8 ah[2], al[2], bh[4], bl[4];
#pragma unroll
            for (int f = 0; f < 2; ++f) {
                int ai = buf * 2048 + (wr * 32 + f * 16 + r16) * 32 + kslot;
                ah[f] = *(const short8*)&smem[ai];
                al[f] = *(const short8*)&smem[4096 + ai];
            }
#pragma unroll
            for (int nf = 0; nf < 4; ++nf) {
                int bi = buf * 4096 + (wc * 64 + nf * 16 + r16) * 32 + kslot;
                bh[nf] = *(const short8*)&smem[8192 + bi];
                bl[nf] = *(const short8*)&smem[16384 + bi];
            }
            if (t + 1 < 32) stage(buf ^ 1, (t + 1) * 32);
            asm volatile("s_waitcnt lgkmcnt(0)" ::: "memory");
            __builtin_amdgcn_sched_barrier(0);
#pragma unroll
            for (int mf = 0; mf < 2; ++mf)
#pragma unroll
                for (int nf = 0; nf < 4; ++nf) {
                    acc[mf][nf] = __builtin_amdgcn_mfma_f32_16x16x32_bf16(ah[mf], bh[nf], acc[mf][nf], 0, 0, 0);
                    acc[mf][nf] = __builtin_amdgcn_mfma_f32_16x16x32_bf16(ah[mf], bl[nf], acc[mf][nf], 0, 0, 0);
                    acc[mf][nf] = __builtin_amdgcn_mfma_f32_16x16x32_bf16(al[mf], bh[nf], acc[mf][nf], 0, 0, 0);
                }
            __builtin_amdgcn_s_barrier();
        }
#pragma unroll
        for (int mf = 0; mf < 2; ++mf)
#pragma unroll
            for (int nf = 0; nf < 4; ++nf)
#pragma unroll
                for (int r = 0; r < 4; ++r) {
                    int m = m0 + wr * 32 + mf * 16 + rg * 4 + r;
                    int nn = n0 + wc * 64 + nf * 16 + r16;
                    float v = acc[mf][nf][r];
                    unsigned short h = f2bf(v);
                    Uhi[(size_t)m * HH + nn] = h;
                    Ulo[(size_t)m * HH + nn] = f2bf(v - bf2f(h));
                }
    } else {
        // ---------- V-GEMM ----------
        const int b2 = bid - 272;
        const int m0 = (b2 / 17) * 64;
        const int n0 = (b2 % 17) * 128;
        f32x4 acc[2][4] = {};

        auto stage = [&](int buf, int kb) {
            lds_load16(wcbf + (size_t)(m0 + srow) * (2 * HH) + kb + scol, &smem[buf * 2048 + tid * 8]);
#pragma unroll
            for (int i = 0; i < 2; ++i) {
                lds_load16(wehi + (size_t)(n0 + i * 64 + srow) * HH + kb + scol,
                           &smem[8192 + buf * 4096 + i * 2048 + tid * 8]);
                lds_load16(welo + (size_t)(n0 + i * 64 + srow) * HH + kb + scol,
                           &smem[16384 + buf * 4096 + i * 2048 + tid * 8]);
            }
        };

        stage(0, 0);
        for (int t = 0; t < 32; ++t) {
            const int buf = t & 1;
            asm volatile("s_waitcnt vmcnt(0)" ::: "memory");
            __builtin_amdgcn_s_barrier();
            short8 af[2], bh[4], bl[4];
#pragma unroll
            for (int f = 0; f < 2; ++f)
                af[f] = *(const short8*)&smem[buf * 2048 + (wr * 32 + f * 16 + r16) * 32 + kslot];
#pragma unroll
            for (int nf = 0; nf < 4; ++nf) {
                int bi = buf * 4096 + (wc * 64 + nf * 16 + r16) * 32 + kslot;
                bh[nf] = *(const short8*)&smem[8192 + bi];
                bl[nf] = *(const short8*)&smem[16384 + bi];
            }
            if (t + 1 < 32) stage(buf ^ 1, (t + 1) * 32);
            asm volatile("s_waitcnt lgkmcnt(0)" ::: "memory");
            __builtin_amdgcn_sched_barrier(0);
#pragma unroll
            for (int mf = 0; mf < 2; ++mf)
#pragma unroll
                for (int nf = 0; nf < 4; ++nf) {
                    acc[mf][nf] = __builtin_amdgcn_mfma_f32_16x16x32_bf16(af[mf], bh[nf], acc[mf][nf], 0, 0, 0);
                    acc[mf][nf] = __builtin_amdgcn_mfma_f32_16x16x32_bf16(af[mf], bl[nf], acc[mf][nf], 0, 0, 0);
                }
            __builtin_amdgcn_s_barrier();
        }
#pragma unroll
        for (int mf = 0; mf < 2; ++mf)
#pragma unroll
            for (int nf = 0; nf < 4; ++nf)
#pragma unroll
                for (int r = 0; r < 4; ++r) {
                    int o = m0 + wr * 32 + mf * 16 + rg * 4 + r;
                    int wrow = n0 + wc * 64 + nf * 16 + r16;
                    int n = wrow / WROWS, li = wrow - n * WROWS;
                    if (n < NB)
                        VT[(size_t)o * VTN + n * 64 + li] = f2bf(acc[mf][nf][r]);
                }
    }
}

// ---------------- K5: QK^T + softmax + gauss -> P hi/lo; side-output ht->bf16 ----------------
__global__ __launch_bounds__(256) void k_attn2(const float* __restrict__ ht,
                                               const unsigned short* __restrict__ Uhi,
                                               const unsigned short* __restrict__ Ulo,
                                               const float* __restrict__ pt,
                                               const int* __restrict__ slen,
                                               unsigned short* __restrict__ Phl,
                                               unsigned short* __restrict__ hbf) {
    __shared__ float sPart[4][32 * 48];
    __shared__ float sScore[32 * 48];

    const int tid = threadIdx.x;
    const int w = tid >> 6, lane = tid & 63;
    const int n = blockIdx.x >> 3, q0 = (blockIdx.x & 7) * 32;
    int ls, lc;
    window_of(pt[n], slen[n], ls, lc);
    const float p = pt[n];
    const int r16 = lane & 15, khalf = lane >> 4, rg = lane >> 4;

    const float* hbase = ht + ((size_t)(n * QQ + q0)) * HH;
    unsigned short* hbbase = hbf + ((size_t)(n * QQ + q0)) * HH;
    const unsigned short* uhbase = Uhi + (size_t)n * WROWS * HH;
    const unsigned short* ulbase = Ulo + (size_t)n * WROWS * HH;

    f32x4 acc[2][3] = {};
#pragma unroll 2
    for (int ks = 0; ks < 8; ++ks) {
        int kcol = w * 256 + ks * 32 + khalf * 8;
        short8 ah[2], al[2];
#pragma unroll
        for (int mf = 0; mf < 2; ++mf) {
            const float* src = hbase + (size_t)(mf * 16 + r16) * HH + kcol;
            f32x4 v0 = *(const f32x4*)src;
            f32x4 v1 = *(const f32x4*)(src + 4);
            float vv[8] = {v0[0], v0[1], v0[2], v0[3], v1[0], v1[1], v1[2], v1[3]};
#pragma unroll
            for (int j = 0; j < 8; ++j) {
                unsigned short hb = f2bf(vv[j]);
                ah[mf][j] = (short)hb;
                al[mf][j] = (short)f2bf(vv[j] - bf2f(hb));
            }
            *(short8*)(hbbase + (size_t)(mf * 16 + r16) * HH + kcol) = ah[mf];
        }
#pragma unroll
        for (int nf = 0; nf < 3; ++nf) {
            size_t uoff = (size_t)(nf * 16 + r16) * HH + kcol;
            short8 bh = *(const short8*)(uhbase + uoff);
            short8 bl = *(const short8*)(ulbase + uoff);
#pragma unroll
            for (int mf = 0; mf < 2; ++mf) {
                acc[mf][nf] = __builtin_amdgcn_mfma_f32_16x16x32_bf16(ah[mf], bh, acc[mf][nf], 0, 0, 0);
                acc[mf][nf] = __builtin_amdgcn_mfma_f32_16x16x32_bf16(ah[mf], bl, acc[mf][nf], 0, 0, 0);
                acc[mf][nf] = __builtin_amdgcn_mfma_f32_16x16x32_bf16(al[mf], bh, acc[mf][nf], 0, 0, 0);
            }
        }
    }
#pragma unroll
    for (int mf = 0; mf < 2; ++mf)
#pragma unroll
        for (int nf = 0; nf < 3; ++nf)
#pragma unroll
            for (int r = 0; r < 4; ++r)
                sPart[w][(mf * 16 + rg * 4 + r) * 48 + nf * 16 + r16] = acc[mf][nf][r];
    __syncthreads();

    {
        int q = tid >> 3, g = tid & 7;
        float sc6[6];
#pragma unroll
        for (int s = 0; s < 6; ++s) {
            int li = g + 8 * s;
            int o = q * 48 + li;
            sc6[s] = sPart[0][o] + sPart[1][o] + sPart[2][o] + sPart[3][o];
        }
        float mx = -1e30f;
#pragma unroll
        for (int s = 0; s < 6; ++s) { int li = g + 8 * s; if (li < lc) mx = fmaxf(mx, sc6[s]); }
        for (int off = 1; off < 8; off <<= 1) mx = fmaxf(mx, __shfl_xor(mx, off, 8));
        float sum = 0.f, ex[6];
#pragma unroll
        for (int s = 0; s < 6; ++s) {
            int li = g + 8 * s;
            float e = (li < lc) ? __expf(sc6[s] - mx) : 0.f;
            ex[s] = e; sum += e;
        }
        for (int off = 1; off < 8; off <<= 1) sum += __shfl_xor(sum, off, 8);
        float inv = 1.0f / sum;
#pragma unroll
        for (int s = 0; s < 6; ++s) {
            int li = g + 8 * s;
            float d = (float)(ls + li) - p;
            float gs = __expf(-(d * d) * (1.0f / 128.0f));
            sScore[q * 48 + li] = ex[s] * inv * gs;
        }
    }
    __syncthreads();

    {
        int row = tid >> 3, c0 = (tid & 7) * 8;
        short8 ph, pl;
#pragma unroll
        for (int j = 0; j < 8; ++j) {
            int c = c0 + j;
            float pv = (c < 48) ? sScore[row * 48 + c] : 0.f;
            unsigned short hb = f2bf(pv);
            ph[j] = (short)hb;
            pl[j] = (short)f2bf(pv - bf2f(hb));
        }
        size_t base = (size_t)(n * QQ + q0 + row) * 128;
        *(short8*)&Phl[base + c0] = ph;
        *(short8*)&Phl[base + 64 + c0] = pl;
    }
}

// ---------------- K6: out = tanh(h @ Wc2^T + P @ VT), 128^2, BK=32, dbuf, 36 K-iters ----------------
// m97-measured operating point: 128^2 tile, BK=32, 16 MFMA + 8 ds_read_b128 per iter.
// Stage/read swizzle identical to k_wgemm's proven BK=32 pattern (2-way banks).
// Iters 0..31: A = hbf K-chunk, B = Wc2 K-chunk. Iters 32..35: A = P chunk, B = VT chunk.
// FP accumulation order identical to the BK=64 version (k 0..1023 in 32-chunks, then PV).
__global__ __launch_bounds__(256) void k_out_gemm128(
    const unsigned short* __restrict__ Ahf,
    const unsigned short* __restrict__ Bt,
    const unsigned short* __restrict__ Phl,
    const unsigned short* __restrict__ VT,
    float* __restrict__ out) {
    __shared__ unsigned short sA[2][4096], sB[2][4096];   // 2 buf x 128x32 bf16 each = 32 KB

    const int tid = threadIdx.x;
    const int wid = tid >> 6, lane = tid & 63;
    const int bid = blockIdx.x;
    const int swz = (bid & 7) * 128 + (bid >> 3);
    const int mt = swz >> 3, nt = swz & 7;
    const int m0 = mt * 128, n0 = nt * 128;
    const int nb = mt >> 1;                            // batch index of this row tile
    const int wr = wid >> 1, wc = wid & 1;
    const int r16 = lane & 15, kg = lane >> 4;

    const int srow = tid >> 2;                         // 0..63 (two passes cover 128 rows)
    const int scol = ((tid & 3) ^ ((tid >> 3) & 3)) * 8;   // XOR-swizzled source k-slot
    const int kslot = (kg ^ ((r16 >> 1) & 3)) * 8;         // matching read slot

    f32x4 acc[4][4] = {};

    auto stage = [&](int buf, int t) {
        if (t < 32) {
            const int kb = t * 32;
#pragma unroll
            for (int i = 0; i < 2; ++i) {
                lds_load16(Ahf + (size_t)(m0 + i * 64 + srow) * HH + kb + scol,
                           &sA[buf][i * 2048 + tid * 8]);
                lds_load16(Bt + (size_t)(n0 + i * 64 + srow) * (2 * HH) + 1024 + kb + scol,
                           &sB[buf][i * 2048 + tid * 8]);
            }
        } else {
            const int pidx = t - 32;
            const int pc = pidx * 32;                  // P col chunk (0,32 = hi; 64,96 = lo)
            const int vc = nb * 64 + (pidx & 1) * 32;  // matching VT col chunk
#pragma unroll
            for (int i = 0; i < 2; ++i) {
                lds_load16(Phl + (size_t)(m0 + i * 64 + srow) * 128 + pc + scol,
                           &sA[buf][i * 2048 + tid * 8]);
                lds_load16(VT + (size_t)(n0 + i * 64 + srow) * VTN + vc + scol,
                           &sB[buf][i * 2048 + tid * 8]);
            }
        }
    };

    stage(0, 0);
    for (int t = 0; t < 36; ++t) {
        const int buf = t & 1;
        asm volatile("s_waitcnt vmcnt(0)" ::: "memory");
        __builtin_amdgcn_s_barrier();
        short8 a[4], b[4];
#pragma unroll
        for (int mq = 0; mq < 4; ++mq)
            a[mq] = *(const short8*)&sA[buf][(wr * 64 + mq * 16 + r16) * 32 + kslot];
#pragma unroll
        for (int nq = 0; nq < 4; ++nq)
            b[nq] = *(const short8*)&sB[buf][(wc * 64 + nq * 16 + r16) * 32 + kslot];
        if (t + 1 < 36) stage(buf ^ 1, t + 1);
        asm volatile("s_waitcnt lgkmcnt(0)" ::: "memory");
        __builtin_amdgcn_sched_barrier(0);
#pragma unroll
        for (int nq = 0; nq < 4; ++nq)
#pragma unroll
            for (int mq = 0; mq < 4; ++mq)
                acc[mq][nq] = __builtin_amdgcn_mfma_f32_16x16x32_bf16(a[mq], b[nq], acc[mq][nq], 0, 0, 0);
        __builtin_amdgcn_s_barrier();
    }

    // ---- epilogue: tanh + store ----
#pragma unroll
    for (int mq = 0; mq < 4; ++mq)
#pragma unroll
        for (int nq = 0; nq < 4; ++nq) {
            int row = m0 + wr * 64 + mq * 16 + kg * 4;
            int col = n0 + wc * 64 + nq * 16 + r16;
#pragma unroll
            for (int r = 0; r < 4; ++r)
                out[(size_t)(row + r) * HH + col] = fast_tanh(acc[mq][nq][r]);
        }
}

extern "C" void kernel_launch(void* const* d_in, const int* in_sizes, int n_in,
                              void* d_out, int out_size, void* d_ws, size_t ws_size,
                              hipStream_t stream) {
    const float* enc  = (const float*)d_in[0];
    const float* ht   = (const float*)d_in[1];
    const int*   slen = (const int*)d_in[2];
    const float* pt   = (const float*)d_in[3];
    const float* Wa   = (const float*)d_in[4];
    const float* Wc   = (const float*)d_in[5];
    float* out = (float*)d_out;

    char* ws = (char*)d_ws;
    unsigned short* wehi = (unsigned short*)(ws + OFF_WEHI);
    unsigned short* welo = (unsigned short*)(ws + OFF_WELO);
    unsigned short* wahi = (unsigned short*)(ws + OFF_WAHI);
    unsigned short* walo = (unsigned short*)(ws + OFF_WALO);
    unsigned short* wcbf = (unsigned short*)(ws + OFF_WCBF);
    unsigned short* hbf  = (unsigned short*)(ws + OFF_HBF);
    unsigned short* uhi  = (unsigned short*)(ws + OFF_UHI);
    unsigned short* ulo  = (unsigned short*)(ws + OFF_ULO);
    unsigned short* phl  = (unsigned short*)(ws + OFF_PHL);
    unsigned short* vt   = (unsigned short*)(ws + OFF_VT);

    hipLaunchKernelGGL(k_prep, dim3(MU + 1024 + 2048), dim3(256), 0, stream,
                       enc, pt, slen, Wa, Wc, wehi, welo, wahi, walo, wcbf);
    hipLaunchKernelGGL(k_wgemm, dim3(544), dim3(256), 0, stream,
                       wehi, welo, wahi, walo, wcbf, uhi, ulo, vt);
    hipLaunchKernelGGL(k_attn2, dim3(NB * 8), dim3(256), 0, stream,
                       ht, uhi, ulo, pt, slen, phl, hbf);
    hipLaunchKernelGGL(k_out_gemm128, dim3(1024), dim3(256), 0, stream,
                       hbf, wcbf, phl, vt, out);
}

// Round 17
// 136.166 us; speedup vs baseline: 1.0387x; 1.0387x over previous
//
#include <hip/hip_runtime.h>
#include <hip/hip_bf16.h>
#include <cstdint>

#define DEVINL __device__ __forceinline__

typedef __attribute__((ext_vector_type(8))) short short8;   // 8 bf16 in 4 VGPRs
typedef __attribute__((ext_vector_type(4))) float f32x4;
typedef __attribute__((ext_vector_type(4))) unsigned short u16x4;

static constexpr int NB = 64, LL = 258, HH = 1024, QQ = 256;
static constexpr int WROWS = 33;          // max window length (2*16+1)
static constexpr int MU = 2176;           // 64*33 = 2112 padded to 17*128
static constexpr int VTN = 4096;          // VT col stride: 64 n * 64 li

// ---- workspace layout (bytes) ----
static constexpr size_t OFF_META = 0;
static constexpr size_t SZ_WE   = (size_t)MU * HH * 2;
static constexpr size_t OFF_WEHI = 1024;
static constexpr size_t OFF_WELO = OFF_WEHI + SZ_WE;
static constexpr size_t OFF_WAHI = OFF_WELO + SZ_WE;
static constexpr size_t OFF_WALO = OFF_WAHI + (size_t)HH * HH * 2;
static constexpr size_t OFF_WCBF = OFF_WALO + (size_t)HH * HH * 2;
static constexpr size_t OFF_HBF  = OFF_WCBF + (size_t)HH * 2 * HH * 2;  // ht bf16 (written by k_attn2)
static constexpr size_t OFF_U    = OFF_HBF + (size_t)NB * QQ * HH * 2;
static constexpr size_t OFF_UHI  = OFF_U;
static constexpr size_t OFF_ULO  = OFF_U + (size_t)MU * HH * 2;
static constexpr size_t OFF_PHL  = OFF_U + (size_t)MU * HH * 4;         // P hi/lo bf16 [16384][128]
static constexpr size_t OFF_VT   = OFF_PHL + (size_t)NB * QQ * 128 * 2; // VT bf16 [1024][4096]

DEVINL unsigned short f2bf(float x) {
    union { float f; uint32_t u; } v; v.f = x;
    uint32_t u = v.u;
    uint32_t r = (u + 0x7FFFu + ((u >> 16) & 1u)) >> 16;
    return (unsigned short)r;
}
DEVINL float bf2f(unsigned short b) {
    union { uint32_t u; float f; } v; v.u = ((uint32_t)b) << 16;
    return v.f;
}

template <typename T>
DEVINL void lds_load16(const T* g, T* l) {
    __builtin_amdgcn_global_load_lds(
        (const __attribute__((address_space(1))) void*)g,
        (__attribute__((address_space(3))) void*)l, 16, 0, 0);
}

DEVINL float fast_tanh(float x) {
    float e = __expf(2.0f * x);
    return 1.0f - 2.0f / (e + 1.0f);
}

DEVINL void window_of(float p, int sl, int& ls, int& lc) {
    float se = (float)sl;
    float s = fmaxf(p - 16.0f, 0.0f);
    float e = fminf(p + 16.0f, se);
    ls = (int)ceilf(s);
    int le = (int)floorf(e); if (le > LL - 1) le = LL - 1;
    lc = le - ls + 1;
    if (lc < 0) lc = 0;
    if (lc > WROWS) lc = WROWS;
}

// ---------------- K_prep: gather + Wa-split + Wc-bf (5248 blocks) ----------------
__global__ __launch_bounds__(256) void k_prep(const float* __restrict__ enc,
                                              const float* __restrict__ pt,
                                              const int* __restrict__ slen,
                                              const float* __restrict__ Wa,
                                              const float* __restrict__ Wc,
                                              unsigned short* __restrict__ wehi,
                                              unsigned short* __restrict__ welo,
                                              unsigned short* __restrict__ wahi,
                                              unsigned short* __restrict__ walo,
                                              unsigned short* __restrict__ wcbf) {
    const int b = blockIdx.x, t = threadIdx.x;
    if (b < MU) {
        int r = b;
        const float* src = nullptr;
        bool valid = false;
        if (r < NB * WROWS) {
            int n = r / WROWS, li = r - n * WROWS;
            int ls, lc;
            window_of(pt[n], slen[n], ls, lc);
            if (li < lc) { valid = true; src = enc + ((size_t)n * LL + ls + li) * HH; }
        }
        f32x4 v;
        if (valid) v = ((const f32x4*)src)[t];
        else { v[0] = 0.f; v[1] = 0.f; v[2] = 0.f; v[3] = 0.f; }
        u16x4 h, l;
#pragma unroll
        for (int j = 0; j < 4; ++j) {
            unsigned short hb = f2bf(v[j]);
            h[j] = hb;
            l[j] = f2bf(v[j] - bf2f(hb));
        }
        size_t o = (size_t)r * HH / 4 + t;
        ((u16x4*)wehi)[o] = h;
        ((u16x4*)welo)[o] = l;
    } else if (b < MU + 1024) {
        int i = (b - MU) * 256 + t;
        f32x4 v = ((const f32x4*)Wa)[i];
        u16x4 h, l;
#pragma unroll
        for (int j = 0; j < 4; ++j) {
            unsigned short hb = f2bf(v[j]);
            h[j] = hb;
            l[j] = f2bf(v[j] - bf2f(hb));
        }
        ((u16x4*)wahi)[i] = h;
        ((u16x4*)walo)[i] = l;
    } else {
        int i = (b - MU - 1024) * 256 + t;
        f32x4 v = ((const f32x4*)Wc)[i];
        u16x4 h;
#pragma unroll
        for (int j = 0; j < 4; ++j) h[j] = f2bf(v[j]);
        ((u16x4*)wcbf)[i] = h;
    }
}

// ---------------- K4: merged U-GEMM + V-GEMM (pure GEMM, 544 blocks) ----------------
__global__ __launch_bounds__(256) void k_wgemm(const unsigned short* __restrict__ wehi,
                                               const unsigned short* __restrict__ welo,
                                               const unsigned short* __restrict__ wahi,
                                               const unsigned short* __restrict__ walo,
                                               const unsigned short* __restrict__ wcbf,
                                               unsigned short* __restrict__ Uhi,
                                               unsigned short* __restrict__ Ulo,
                                               unsigned short* __restrict__ VT) {
    __shared__ unsigned short smem[24576];   // 48 KB
    const int tid = threadIdx.x;
    const int bid = blockIdx.x;

    const int w = tid >> 6, lane = tid & 63;
    const int wr = w >> 1, wc = w & 1;
    const int r16 = lane & 15, khalf = lane >> 4, rg = lane >> 4;
    const int srow = tid >> 2;
    const int scol = ((tid & 3) ^ ((tid >> 3) & 3)) * 8;
    const int kslot = (khalf ^ ((r16 >> 1) & 3)) * 8;

    if (bid < 272) {
        // ---------- U-GEMM ----------
        const int m0 = (bid >> 3) * 64;
        const int n0 = (bid & 7) * 128;
        f32x4 acc[2][4] = {};

        auto stage = [&](int buf, int kb) {
            lds_load16(wehi + (size_t)(m0 + srow) * HH + kb + scol, &smem[buf * 2048 + tid * 8]);
            lds_load16(welo + (size_t)(m0 + srow) * HH + kb + scol, &smem[4096 + buf * 2048 + tid * 8]);
#pragma unroll
            for (int i = 0; i < 2; ++i) {
                lds_load16(wahi + (size_t)(n0 + i * 64 + srow) * HH + kb + scol,
                           &smem[8192 + buf * 4096 + i * 2048 + tid * 8]);
                lds_load16(walo + (size_t)(n0 + i * 64 + srow) * HH + kb + scol,
                           &smem[16384 + buf * 4096 + i * 2048 + tid * 8]);
            }
        };

        stage(0, 0);
        for (int t = 0; t < 32; ++t) {
            const int buf = t & 1;
            asm volatile("s_waitcnt vmcnt(0)" ::: "memory");
            __builtin_amdgcn_s_barrier();
            short8 ah[2], al[2], bh[4], bl[4];
#pragma unroll
            for (int f = 0; f < 2; ++f) {
                int ai = buf * 2048 + (wr * 32 + f * 16 + r16) * 32 + kslot;
                ah[f] = *(const short8*)&smem[ai];
                al[f] = *(const short8*)&smem[4096 + ai];
            }
#pragma unroll
            for (int nf = 0; nf < 4; ++nf) {
                int bi = buf * 4096 + (wc * 64 + nf * 16 + r16) * 32 + kslot;
                bh[nf] = *(const short8*)&smem[8192 + bi];
                bl[nf] = *(const short8*)&smem[16384 + bi];
            }
            if (t + 1 < 32) stage(buf ^ 1, (t + 1) * 32);
            asm volatile("s_waitcnt lgkmcnt(0)" ::: "memory");
            __builtin_amdgcn_sched_barrier(0);
#pragma unroll
            for (int mf = 0; mf < 2; ++mf)
#pragma unroll
                for (int nf = 0; nf < 4; ++nf) {
                    acc[mf][nf] = __builtin_amdgcn_mfma_f32_16x16x32_bf16(ah[mf], bh[nf], acc[mf][nf], 0, 0, 0);
                    acc[mf][nf] = __builtin_amdgcn_mfma_f32_16x16x32_bf16(ah[mf], bl[nf], acc[mf][nf], 0, 0, 0);
                    acc[mf][nf] = __builtin_amdgcn_mfma_f32_16x16x32_bf16(al[mf], bh[nf], acc[mf][nf], 0, 0, 0);
                }
            __builtin_amdgcn_s_barrier();
        }
#pragma unroll
        for (int mf = 0; mf < 2; ++mf)
#pragma unroll
            for (int nf = 0; nf < 4; ++nf)
#pragma unroll
                for (int r = 0; r < 4; ++r) {
                    int m = m0 + wr * 32 + mf * 16 + rg * 4 + r;
                    int nn = n0 + wc * 64 + nf * 16 + r16;
                    float v = acc[mf][nf][r];
                    unsigned short h = f2bf(v);
                    Uhi[(size_t)m * HH + nn] = h;
                    Ulo[(size_t)m * HH + nn] = f2bf(v - bf2f(h));
                }
    } else {
        // ---------- V-GEMM ----------
        const int b2 = bid - 272;
        const int m0 = (b2 / 17) * 64;
        const int n0 = (b2 % 17) * 128;
        f32x4 acc[2][4] = {};

        auto stage = [&](int buf, int kb) {
            lds_load16(wcbf + (size_t)(m0 + srow) * (2 * HH) + kb + scol, &smem[buf * 2048 + tid * 8]);
#pragma unroll
            for (int i = 0; i < 2; ++i) {
                lds_load16(wehi + (size_t)(n0 + i * 64 + srow) * HH + kb + scol,
                           &smem[8192 + buf * 4096 + i * 2048 + tid * 8]);
                lds_load16(welo + (size_t)(n0 + i * 64 + srow) * HH + kb + scol,
                           &smem[16384 + buf * 4096 + i * 2048 + tid * 8]);
            }
        };

        stage(0, 0);
        for (int t = 0; t < 32; ++t) {
            const int buf = t & 1;
            asm volatile("s_waitcnt vmcnt(0)" ::: "memory");
            __builtin_amdgcn_s_barrier();
            short8 af[2], bh[4], bl[4];
#pragma unroll
            for (int f = 0; f < 2; ++f)
                af[f] = *(const short8*)&smem[buf * 2048 + (wr * 32 + f * 16 + r16) * 32 + kslot];
#pragma unroll
            for (int nf = 0; nf < 4; ++nf) {
                int bi = buf * 4096 + (wc * 64 + nf * 16 + r16) * 32 + kslot;
                bh[nf] = *(const short8*)&smem[8192 + bi];
                bl[nf] = *(const short8*)&smem[16384 + bi];
            }
            if (t + 1 < 32) stage(buf ^ 1, (t + 1) * 32);
            asm volatile("s_waitcnt lgkmcnt(0)" ::: "memory");
            __builtin_amdgcn_sched_barrier(0);
#pragma unroll
            for (int mf = 0; mf < 2; ++mf)
#pragma unroll
                for (int nf = 0; nf < 4; ++nf) {
                    acc[mf][nf] = __builtin_amdgcn_mfma_f32_16x16x32_bf16(af[mf], bh[nf], acc[mf][nf], 0, 0, 0);
                    acc[mf][nf] = __builtin_amdgcn_mfma_f32_16x16x32_bf16(af[mf], bl[nf], acc[mf][nf], 0, 0, 0);
                }
            __builtin_amdgcn_s_barrier();
        }
#pragma unroll
        for (int mf = 0; mf < 2; ++mf)
#pragma unroll
            for (int nf = 0; nf < 4; ++nf)
#pragma unroll
                for (int r = 0; r < 4; ++r) {
                    int o = m0 + wr * 32 + mf * 16 + rg * 4 + r;
                    int wrow = n0 + wc * 64 + nf * 16 + r16;
                    int n = wrow / WROWS, li = wrow - n * WROWS;
                    if (n < NB)
                        VT[(size_t)o * VTN + n * 64 + li] = f2bf(acc[mf][nf][r]);
                }
    }
}

// ---------------- K5: QK^T + softmax + gauss -> P hi/lo; side-output ht->bf16 ----------------
__global__ __launch_bounds__(256) void k_attn2(const float* __restrict__ ht,
                                               const unsigned short* __restrict__ Uhi,
                                               const unsigned short* __restrict__ Ulo,
                                               const float* __restrict__ pt,
                                               const int* __restrict__ slen,
                                               unsigned short* __restrict__ Phl,
                                               unsigned short* __restrict__ hbf) {
    __shared__ float sPart[4][32 * 48];
    __shared__ float sScore[32 * 48];

    const int tid = threadIdx.x;
    const int w = tid >> 6, lane = tid & 63;
    const int n = blockIdx.x >> 3, q0 = (blockIdx.x & 7) * 32;
    int ls, lc;
    window_of(pt[n], slen[n], ls, lc);
    const float p = pt[n];
    const int r16 = lane & 15, khalf = lane >> 4, rg = lane >> 4;

    const float* hbase = ht + ((size_t)(n * QQ + q0)) * HH;
    unsigned short* hbbase = hbf + ((size_t)(n * QQ + q0)) * HH;
    const unsigned short* uhbase = Uhi + (size_t)n * WROWS * HH;
    const unsigned short* ulbase = Ulo + (size_t)n * WROWS * HH;

    f32x4 acc[2][3] = {};
#pragma unroll 2
    for (int ks = 0; ks < 8; ++ks) {
        int kcol = w * 256 + ks * 32 + khalf * 8;
        short8 ah[2], al[2];
#pragma unroll
        for (int mf = 0; mf < 2; ++mf) {
            const float* src = hbase + (size_t)(mf * 16 + r16) * HH + kcol;
            f32x4 v0 = *(const f32x4*)src;
            f32x4 v1 = *(const f32x4*)(src + 4);
            float vv[8] = {v0[0], v0[1], v0[2], v0[3], v1[0], v1[1], v1[2], v1[3]};
#pragma unroll
            for (int j = 0; j < 8; ++j) {
                unsigned short hb = f2bf(vv[j]);
                ah[mf][j] = (short)hb;
                al[mf][j] = (short)f2bf(vv[j] - bf2f(hb));
            }
            *(short8*)(hbbase + (size_t)(mf * 16 + r16) * HH + kcol) = ah[mf];
        }
#pragma unroll
        for (int nf = 0; nf < 3; ++nf) {
            size_t uoff = (size_t)(nf * 16 + r16) * HH + kcol;
            short8 bh = *(const short8*)(uhbase + uoff);
            short8 bl = *(const short8*)(ulbase + uoff);
#pragma unroll
            for (int mf = 0; mf < 2; ++mf) {
                acc[mf][nf] = __builtin_amdgcn_mfma_f32_16x16x32_bf16(ah[mf], bh, acc[mf][nf], 0, 0, 0);
                acc[mf][nf] = __builtin_amdgcn_mfma_f32_16x16x32_bf16(ah[mf], bl, acc[mf][nf], 0, 0, 0);
                acc[mf][nf] = __builtin_amdgcn_mfma_f32_16x16x32_bf16(al[mf], bh, acc[mf][nf], 0, 0, 0);
            }
        }
    }
#pragma unroll
    for (int mf = 0; mf < 2; ++mf)
#pragma unroll
        for (int nf = 0; nf < 3; ++nf)
#pragma unroll
            for (int r = 0; r < 4; ++r)
                sPart[w][(mf * 16 + rg * 4 + r) * 48 + nf * 16 + r16] = acc[mf][nf][r];
    __syncthreads();

    {
        int q = tid >> 3, g = tid & 7;
        float sc6[6];
#pragma unroll
        for (int s = 0; s < 6; ++s) {
            int li = g + 8 * s;
            int o = q * 48 + li;
            sc6[s] = sPart[0][o] + sPart[1][o] + sPart[2][o] + sPart[3][o];
        }
        float mx = -1e30f;
#pragma unroll
        for (int s = 0; s < 6; ++s) { int li = g + 8 * s; if (li < lc) mx = fmaxf(mx, sc6[s]); }
        for (int off = 1; off < 8; off <<= 1) mx = fmaxf(mx, __shfl_xor(mx, off, 8));
        float sum = 0.f, ex[6];
#pragma unroll
        for (int s = 0; s < 6; ++s) {
            int li = g + 8 * s;
            float e = (li < lc) ? __expf(sc6[s] - mx) : 0.f;
            ex[s] = e; sum += e;
        }
        for (int off = 1; off < 8; off <<= 1) sum += __shfl_xor(sum, off, 8);
        float inv = 1.0f / sum;
#pragma unroll
        for (int s = 0; s < 6; ++s) {
            int li = g + 8 * s;
            float d = (float)(ls + li) - p;
            float gs = __expf(-(d * d) * (1.0f / 128.0f));
            sScore[q * 48 + li] = ex[s] * inv * gs;
        }
    }
    __syncthreads();

    {
        int row = tid >> 3, c0 = (tid & 7) * 8;
        short8 ph, pl;
#pragma unroll
        for (int j = 0; j < 8; ++j) {
            int c = c0 + j;
            float pv = (c < 48) ? sScore[row * 48 + c] : 0.f;
            unsigned short hb = f2bf(pv);
            ph[j] = (short)hb;
            pl[j] = (short)f2bf(pv - bf2f(hb));
        }
        size_t base = (size_t)(n * QQ + q0 + row) * 128;
        *(short8*)&Phl[base + c0] = ph;
        *(short8*)&Phl[base + 64 + c0] = pl;
    }
}

// ---------------- K6: out = tanh(h @ Wc2^T + P @ VT), 128^2, BK=64, dbuf counted-vmcnt ----------------
// r15 structure + cross-iteration pipeline: stage(t+1) issued BEFORE waiting; vmcnt(8)
// waits only for stage(t)'s 8 loads (stage(t+1)'s 8 remain in flight under the MFMAs).
// Buffer safety: buf^1 staged at iter t was last read at iter t-1 (lgkmcnt(0) before MFMA,
// trailing barrier) -> no race. FP accumulation order identical to r15 (absmax bit-identical).
__global__ __launch_bounds__(256) void k_out_gemm128(
    const unsigned short* __restrict__ Ahf,
    const unsigned short* __restrict__ Bt,
    const unsigned short* __restrict__ Phl,
    const unsigned short* __restrict__ VT,
    float* __restrict__ out) {
    __shared__ unsigned short sA[2][128 * 64], sB[2][128 * 64];   // 64 KB

    const int tid = threadIdx.x;
    const int wid = tid >> 6, lane = tid & 63;
    const int bid = blockIdx.x;
    const int swz = (bid & 7) * 128 + (bid >> 3);
    const int mt = swz >> 3, nt = swz & 7;
    const int m0 = mt * 128, n0 = nt * 128;
    const int nb = mt >> 1;                            // batch index of this row tile
    const int wr = wid >> 1, wc = wid & 1;
    const int r16 = lane & 15, kg = lane >> 4;

    const int srow8 = lane >> 3;
    const int kswz = ((lane & 7) ^ srow8) * 8;

    f32x4 acc[4][4] = {};

    auto stage = [&](int buf, int t) {                 // 8 loads per thread
        if (t < 16) {
            const int kb = t * 64;
#pragma unroll
            for (int i = 0; i < 4; ++i) {
                int row = i * 32 + wid * 8 + srow8;
                lds_load16(Ahf + (size_t)(m0 + row) * HH + kb + kswz,
                           &sA[buf][i * 2048 + wid * 512]);
                lds_load16(Bt + (size_t)(n0 + row) * (2 * HH) + 1024 + kb + kswz,
                           &sB[buf][i * 2048 + wid * 512]);
            }
        } else {
            const int pc = (t - 16) * 64;              // 0 = P hi, 64 = P lo
#pragma unroll
            for (int i = 0; i < 4; ++i) {
                int row = i * 32 + wid * 8 + srow8;
                lds_load16(Phl + (size_t)(m0 + row) * 128 + pc + kswz,
                           &sA[buf][i * 2048 + wid * 512]);
                lds_load16(VT + (size_t)(n0 + row) * VTN + nb * 64 + kswz,
                           &sB[buf][i * 2048 + wid * 512]);
            }
        }
    };

    stage(0, 0);
    for (int t = 0; t < 18; ++t) {
        const int buf = t & 1;
        if (t + 1 < 18) {
            stage(buf ^ 1, t + 1);                     // issue next-tile loads first
            asm volatile("s_waitcnt vmcnt(8)" ::: "memory");   // stage(t) done; 8 in flight
        } else {
            asm volatile("s_waitcnt vmcnt(0)" ::: "memory");
        }
        __builtin_amdgcn_s_barrier();

        short8 a[4][2];
#pragma unroll
        for (int mq = 0; mq < 4; ++mq)
#pragma unroll
            for (int ks = 0; ks < 2; ++ks)
                a[mq][ks] = *(const short8*)&sA[buf][(wr * 64 + mq * 16 + r16) * 64 +
                                                     (((ks * 4 + kg) ^ (r16 & 7)) * 8)];
        short8 b[4][2];
#pragma unroll
        for (int nq = 0; nq < 4; ++nq) {
            b[nq][0] = *(const short8*)&sB[buf][(wc * 64 + nq * 16 + r16) * 64 +
                                               (((0 + kg) ^ (r16 & 7)) * 8)];
            b[nq][1] = *(const short8*)&sB[buf][(wc * 64 + nq * 16 + r16) * 64 +
                                               (((4 + kg) ^ (r16 & 7)) * 8)];
        }
        asm volatile("s_waitcnt lgkmcnt(0)" ::: "memory");
        __builtin_amdgcn_sched_barrier(0);
#pragma unroll
        for (int nq = 0; nq < 4; ++nq)
#pragma unroll
            for (int mq = 0; mq < 4; ++mq) {
                acc[mq][nq] = __builtin_amdgcn_mfma_f32_16x16x32_bf16(a[mq][0], b[nq][0], acc[mq][nq], 0, 0, 0);
                acc[mq][nq] = __builtin_amdgcn_mfma_f32_16x16x32_bf16(a[mq][1], b[nq][1], acc[mq][nq], 0, 0, 0);
            }
        __builtin_amdgcn_s_barrier();                  // all reads of buf done -> safe to restage
    }

    // ---- epilogue: tanh + store ----
#pragma unroll
    for (int mq = 0; mq < 4; ++mq)
#pragma unroll
        for (int nq = 0; nq < 4; ++nq) {
            int row = m0 + wr * 64 + mq * 16 + kg * 4;
            int col = n0 + wc * 64 + nq * 16 + r16;
#pragma unroll
            for (int r = 0; r < 4; ++r)
                out[(size_t)(row + r) * HH + col] = fast_tanh(acc[mq][nq][r]);
        }
}

extern "C" void kernel_launch(void* const* d_in, const int* in_sizes, int n_in,
                              void* d_out, int out_size, void* d_ws, size_t ws_size,
                              hipStream_t stream) {
    const float* enc  = (const float*)d_in[0];
    const float* ht   = (const float*)d_in[1];
    const int*   slen = (const int*)d_in[2];
    const float* pt   = (const float*)d_in[3];
    const float* Wa   = (const float*)d_in[4];
    const float* Wc   = (const float*)d_in[5];
    float* out = (float*)d_out;

    char* ws = (char*)d_ws;
    unsigned short* wehi = (unsigned short*)(ws + OFF_WEHI);
    unsigned short* welo = (unsigned short*)(ws + OFF_WELO);
    unsigned short* wahi = (unsigned short*)(ws + OFF_WAHI);
    unsigned short* walo = (unsigned short*)(ws + OFF_WALO);
    unsigned short* wcbf = (unsigned short*)(ws + OFF_WCBF);
    unsigned short* hbf  = (unsigned short*)(ws + OFF_HBF);
    unsigned short* uhi  = (unsigned short*)(ws + OFF_UHI);
    unsigned short* ulo  = (unsigned short*)(ws + OFF_ULO);
    unsigned short* phl  = (unsigned short*)(ws + OFF_PHL);
    unsigned short* vt   = (unsigned short*)(ws + OFF_VT);

    hipLaunchKernelGGL(k_prep, dim3(MU + 1024 + 2048), dim3(256), 0, stream,
                       enc, pt, slen, Wa, Wc, wehi, welo, wahi, walo, wcbf);
    hipLaunchKernelGGL(k_wgemm, dim3(544), dim3(256), 0, stream,
                       wehi, welo, wahi, walo, wcbf, uhi, ulo, vt);
    hipLaunchKernelGGL(k_attn2, dim3(NB * 8), dim3(256), 0, stream,
                       ht, uhi, ulo, pt, slen, phl, hbf);
    hipLaunchKernelGGL(k_out_gemm128, dim3(1024), dim3(256), 0, stream,
                       hbf, wcbf, phl, vt, out);
}